// Round 5
// baseline (414.311 us; speedup 1.0000x reference)
//
#include <hip/hip_runtime.h>
#include <math.h>

#define B_    2
#define TU_   1024
#define D_    80
#define H_    8
#define DH_   10
#define FFN_  2048
#define SEG_  32
#define RC_   8
#define LC_   50
#define NSEG_ 32
#define RCT_  256
#define L_    1280
#define NLAYERS_ 4
#define OUTD_ 768
#define EPS_  1e-5f
#define SCALE_ 0.31622776601683794f
#define NR_   (B_*L_)                 // 2560
#define KP_   96                      // K pad 80->96

typedef __attribute__((ext_vector_type(8))) short bf16x8;
typedef __attribute__((ext_vector_type(4))) float f32x4;
typedef unsigned short ushort_t;

__device__ inline ushort_t f2bf(float f) {
  union { float f; unsigned u; } x; x.f = f;
  unsigned r = x.u + 0x7fffu + ((x.u >> 16) & 1u);   // RNE
  return (ushort_t)(r >> 16);
}

// ============ one-shot weight prep: transpose+bf16 (+scale/pad folds) ============
#define S1_ (NLAYERS_*FFN_*KP_)        // w1T [l][n2048][k96]
#define S2_ (NLAYERS_*D_*FFN_)         // w2T [l][n80][k2048]
#define S3_ (NLAYERS_*256*KP_)         // wqkvT [l][n256][k96] (scale folded in q cols)
#define S4_ (NLAYERS_*D_*KP_)          // woT [l][n80][k96]
#define S5_ (OUTD_*KP_)                // pwT [n768][k96]
#define S6_ (NLAYERS_*240)             // bqkv fp32 [l][240]
#define WPREP_N_ (S1_+S2_+S3_+S4_+S5_+S6_)

__global__ void k_wprep(const float* __restrict__ w1, const float* __restrict__ w2,
    const float* __restrict__ wq, const float* __restrict__ wkv,
    const float* __restrict__ wo, const float* __restrict__ pw,
    const float* __restrict__ bq, const float* __restrict__ bkv,
    ushort_t* __restrict__ w1T, ushort_t* __restrict__ w2T,
    ushort_t* __restrict__ wqkvT, ushort_t* __restrict__ woT,
    ushort_t* __restrict__ pwT, float* __restrict__ bqkv) {
  int idx = blockIdx.x * blockDim.x + threadIdx.x;
  if (idx < S1_) {
    int k = idx % KP_, n = (idx / KP_) % FFN_, l = idx / (KP_*FFN_);
    w1T[idx] = (k < D_) ? f2bf(w1[(l*D_ + k)*FFN_ + n]) : 0;
    return;
  }
  idx -= S1_;
  if (idx < S2_) {
    int k = idx % FFN_, n = (idx / FFN_) % D_, l = idx / (FFN_*D_);
    w2T[idx] = f2bf(w2[(l*FFN_ + k)*D_ + n]);
    return;
  }
  idx -= S2_;
  if (idx < S3_) {
    int k = idx % KP_, n = (idx / KP_) % 256, l = idx / (KP_*256);
    float v = 0.f;
    if (k < D_ && n < 240) {
      if (n < D_) v = wq[(l*D_ + k)*D_ + n] * SCALE_;
      else        v = wkv[(l*D_ + k)*2*D_ + (n - D_)];
    }
    wqkvT[idx] = f2bf(v);
    return;
  }
  idx -= S3_;
  if (idx < S4_) {
    int k = idx % KP_, n = (idx / KP_) % D_, l = idx / (KP_*D_);
    woT[idx] = (k < D_) ? f2bf(wo[(l*D_ + k)*D_ + n]) : 0;
    return;
  }
  idx -= S4_;
  if (idx < S5_) {
    int k = idx % KP_, n = idx / KP_;
    pwT[idx] = (k < D_) ? f2bf(pw[k*OUTD_ + n]) : 0;
    return;
  }
  idx -= S5_;
  if (idx < S6_) {
    int c = idx % 240, l = idx / 240;
    bqkv[idx] = (c < D_) ? bq[l*D_ + c] * SCALE_ : bkv[l*2*D_ + (c - D_)];
  }
}

// ============ build x (gather) + layer-0 LN_in -> xnbf ============
__global__ __launch_bounds__(128) void k_build_ln(const float* __restrict__ mel,
    const float* __restrict__ lw, const float* __restrict__ lb,
    float* __restrict__ x, ushort_t* __restrict__ xnbf) {
  int row = blockIdx.x, tid = threadIdx.x;
  int b = row / L_, i = row % L_;
  int srow;
  if (i < RCT_) { int seg = i / RC_, j = i % RC_; srow = (seg+1)*SEG_ + j; }
  else          { srow = i - RCT_; }
  __shared__ float s1[128], s2[128];
  float v = (tid < D_) ? mel[(b*(TU_+RC_) + srow)*D_ + tid] : 0.f;
  if (tid < D_) x[row*D_ + tid] = v;
  s1[tid] = v; s2[tid] = v*v;
  __syncthreads();
  for (int off = 64; off > 0; off >>= 1) {
    if (tid < off) { s1[tid] += s1[tid+off]; s2[tid] += s2[tid+off]; }
    __syncthreads();
  }
  float mean = s1[0] * (1.f/D_);
  float var  = s2[0] * (1.f/D_) - mean*mean;
  float inv  = rsqrtf(var + EPS_);
  if (tid < D_)       xnbf[row*KP_ + tid] = f2bf((v - mean) * inv * lw[tid] + lb[tid]);
  else if (tid < KP_) xnbf[row*KP_ + tid] = 0;
}

// ============ MEGA attention kernel: QKV(window) + 8-head attn + WO + res + LN_ff ============
// grid (NSEG, B), 512 thr (8 waves). Block owns segment's 40 query rows exclusively.
__global__ __launch_bounds__(512) void k_attn_mega(const ushort_t* __restrict__ xnbf,
    const float* __restrict__ x,
    const ushort_t* __restrict__ wqkvT, const float* __restrict__ bqkv,
    const ushort_t* __restrict__ woT, const float* __restrict__ bo,
    const float* __restrict__ lw, const float* __restrict__ lb,
    float* __restrict__ res, ushort_t* __restrict__ hnbf) {
  int seg = blockIdx.x, b = blockIdx.y;
  int tid = threadIdx.x;
  int wv = tid >> 6, lane = tid & 63;
  int r = lane & 15, g = lane >> 4;
  int s0 = seg*SEG_ - LC_; if (s0 < 0) s0 = 0;
  int nu = (seg+1)*SEG_ - s0;        // 32..82
  int M  = RC_ + nu;                 // 40..90 rows = keys; queries subset
  int qoff = RC_ + seg*SEG_ - s0;    // local row of query index 8
  int Mt = (M + 15) >> 4;            // 3..6 M-frags
  int base = b*L_;

  __shared__ float qsh[40][D_];
  __shared__ float ksh[90][D_];
  __shared__ float vsh[90][D_];
  __shared__ float Ssh[4][40][90];
  __shared__ float inv_sh[4][40];
  __shared__ ushort_t attsh[48][KP_];

  // zero attsh (pads: rows 40..47, cols 80..95)
  for (int e = tid; e < 48*KP_; e += 512) ((ushort_t*)attsh)[e] = 0;

  // ---- phase 1: QKV for the M window rows (two contiguous ranges) ----
  int ntiles = Mt * 15;
  for (int t = wv; t < ntiles; t += 8) {
    int mi = t / 15, ni = t - mi*15;
    int lr = mi*16 + r;
    int grow;
    if (lr < RC_)    grow = base + seg*RC_ + lr;
    else if (lr < M) grow = base + RCT_ + s0 + (lr - RC_);
    else             grow = base;                     // pad row, result ignored
    const ushort_t* Ap = xnbf + (size_t)grow*KP_ + g*8;
    const ushort_t* Bp = wqkvT + (size_t)(ni*16 + r)*KP_ + g*8;
    f32x4 acc = {};
    #pragma unroll
    for (int ks = 0; ks < KP_; ks += 32) {
      bf16x8 a  = *(const bf16x8*)(Ap + ks);
      bf16x8 bb = *(const bf16x8*)(Bp + ks);
      acc = __builtin_amdgcn_mfma_f32_16x16x32_bf16(a, bb, acc, 0, 0, 0);
    }
    int col = ni*16 + r;
    float bc = bqkv[col];
    #pragma unroll
    for (int rr = 0; rr < 4; ++rr) {
      int lrow = mi*16 + g*4 + rr;
      if (lrow >= M) continue;
      float v = acc[rr] + bc;
      if (col < D_) {
        int qi = -1;
        if (lrow < RC_) qi = lrow;
        else if (lrow >= qoff) qi = RC_ + (lrow - qoff);
        if (qi >= 0) qsh[qi][col] = v;
      } else if (col < 2*D_) {
        ksh[lrow][col - D_] = v;
      } else {
        vsh[lrow][col - 2*D_] = v;
      }
    }
  }
  __syncthreads();

  // ---- phase 2: attention, two head-groups of 4 (S fp32 in LDS) ----
  for (int hg = 0; hg < 2; ++hg) {
    for (int hh = 0; hh < 4; ++hh) {
      int h = hg*4 + hh;
      for (int e = tid; e < 40*96; e += 512) {
        int qi = e / 96, kk = e - qi*96;
        if (kk < M) {
          float s = 0.f;
          #pragma unroll
          for (int d = 0; d < DH_; ++d) s += qsh[qi][h*DH_+d] * ksh[kk][h*DH_+d];
          Ssh[hh][qi][kk] = s;
        }
      }
    }
    __syncthreads();
    if (tid < 320) {
      int row = tid >> 1, j = tid & 1;
      int hh = row / 40, qi = row - hh*40;
      float pm = -INFINITY;
      for (int kk = j; kk < M; kk += 2) pm = fmaxf(pm, Ssh[hh][qi][kk]);
      pm = fmaxf(pm, __shfl_xor(pm, 1, 2));
      float ps = 0.f;
      for (int kk = j; kk < M; kk += 2) {
        float e = expf(Ssh[hh][qi][kk] - pm);
        Ssh[hh][qi][kk] = e;
        ps += e;
      }
      ps += __shfl_xor(ps, 1, 2);
      if (j == 0) inv_sh[hh][qi] = 1.f / ps;
    }
    __syncthreads();
    for (int o = tid; o < 1600; o += 512) {
      int hh = o / 400, rem = o - hh*400;
      int qi = rem / 10, d = rem - qi*10;
      int h = hg*4 + hh;
      float a = 0.f;
      for (int kk = 0; kk < M; ++kk) a += Ssh[hh][qi][kk] * vsh[kk][h*DH_+d];
      attsh[qi][h*DH_+d] = f2bf(a * inv_sh[hh][qi]);
    }
    __syncthreads();
  }

  // ---- phase 3: WO MFMA + bias + residual + LN_ff (waves 0..2) ----
  if (wv < 3) {
    int mi = wv;
    f32x4 acc[5] = {};
    #pragma unroll
    for (int ks = 0; ks < KP_; ks += 32) {
      bf16x8 a = *(const bf16x8*)(&attsh[mi*16 + r][ks + g*8]);
      #pragma unroll
      for (int nf = 0; nf < 5; ++nf) {
        bf16x8 bb = *(const bf16x8*)(woT + (size_t)(nf*16 + r)*KP_ + ks + g*8);
        acc[nf] = __builtin_amdgcn_mfma_f32_16x16x32_bf16(a, bb, acc[nf], 0, 0, 0);
      }
    }
    #pragma unroll
    for (int rr = 0; rr < 4; ++rr) {
      int qi = mi*16 + g*4 + rr;            // uniform across the 16-lane shfl group
      if (qi < 40) {
        int grow = (qi < RC_) ? base + seg*RC_ + qi
                              : base + RCT_ + seg*SEG_ + (qi - RC_);
        float v[5], s = 0.f, ss = 0.f;
        #pragma unroll
        for (int nf = 0; nf < 5; ++nf) {
          int col = nf*16 + r;
          v[nf] = acc[nf][rr] + bo[col] + x[(size_t)grow*D_ + col];
          res[(size_t)grow*D_ + col] = v[nf];
          s += v[nf]; ss += v[nf]*v[nf];
        }
        s  += __shfl_xor(s, 1, 16);  ss += __shfl_xor(ss, 1, 16);
        s  += __shfl_xor(s, 2, 16);  ss += __shfl_xor(ss, 2, 16);
        s  += __shfl_xor(s, 4, 16);  ss += __shfl_xor(ss, 4, 16);
        s  += __shfl_xor(s, 8, 16);  ss += __shfl_xor(ss, 8, 16);
        float mean = s * (1.f/D_);
        float var  = ss * (1.f/D_) - mean*mean;
        float inv  = rsqrtf(var + EPS_);
        #pragma unroll
        for (int nf = 0; nf < 5; ++nf) {
          int col = nf*16 + r;
          hnbf[(size_t)grow*KP_ + col] = f2bf((v[nf] - mean) * inv * lw[col] + lb[col]);
        }
        hnbf[(size_t)grow*KP_ + D_ + r] = 0;   // pad cols
      }
    }
  }
}

// ============ fused FFN: FFN1 (per-wave 256 cols) -> LDS transpose -> FFN2 ->
//              reduce + bias + residual + LN_out -> x, LN_in(next)/plain -> xnbf ============
// grid 160, 512 thr. 16 rows per block; wave wv owns ff1 cols [wv*256, wv*256+256).
__global__ __launch_bounds__(512) void k_ffn_fused(const ushort_t* __restrict__ hnbf,
    const ushort_t* __restrict__ w1T, const float* __restrict__ b1,
    const ushort_t* __restrict__ w2T, const float* __restrict__ b2,
    const float* __restrict__ res,
    const float* __restrict__ low, const float* __restrict__ lob,
    const float* __restrict__ liw, const float* __restrict__ lib, int mode,
    float* __restrict__ x, ushort_t* __restrict__ xnbf) {
  int tid = threadIdx.x;
  int wv = tid >> 6, lane = tid & 63;
  int r = lane & 15, g = lane >> 4;
  int bm = blockIdx.x * 16;
  __shared__ ushort_t hnsh[16][KP_];
  __shared__ ushort_t ff1sh[8][16][264];     // +8 pad: conflict-free transpose
  __shared__ float red[8][16][D_];

  if (tid < 192) {               // 16 rows x 96 = 192 x bf16x8
    int row = tid / 12, c = (tid % 12) * 8;
    *(bf16x8*)&hnsh[row][c] = *(const bf16x8*)(hnbf + (size_t)(bm+row)*KP_ + c);
  }
  __syncthreads();

  // FFN1: M=16 x N=256(per wave) x K=96
  f32x4 acc1[16];
  #pragma unroll
  for (int ni = 0; ni < 16; ++ni) acc1[ni] = (f32x4){0.f,0.f,0.f,0.f};
  int nbase = wv*256;
  #pragma unroll
  for (int ks = 0; ks < KP_; ks += 32) {
    bf16x8 a = *(const bf16x8*)(&hnsh[r][ks + g*8]);
    #pragma unroll
    for (int ni = 0; ni < 16; ++ni) {
      bf16x8 bb = *(const bf16x8*)(w1T + (size_t)(nbase + ni*16 + r)*KP_ + ks + g*8);
      acc1[ni] = __builtin_amdgcn_mfma_f32_16x16x32_bf16(a, bb, acc1[ni], 0, 0, 0);
    }
  }
  #pragma unroll
  for (int ni = 0; ni < 16; ++ni) {
    int col = nbase + ni*16 + r;
    float bc = b1[col];
    #pragma unroll
    for (int rr = 0; rr < 4; ++rr)
      ff1sh[wv][g*4 + rr][ni*16 + r] = f2bf(fmaxf(acc1[ni][rr] + bc, 0.f));
  }
  // same-wave write->read: compiler inserts lgkmcnt wait; no block barrier needed

  // FFN2: M=16 x N=80 x K=256 (this wave's chunk)
  f32x4 acc2[5] = {};
  #pragma unroll
  for (int ks = 0; ks < 256; ks += 32) {
    bf16x8 a = *(const bf16x8*)(&ff1sh[wv][r][ks + g*8]);
    #pragma unroll
    for (int nf = 0; nf < 5; ++nf) {
      bf16x8 bb = *(const bf16x8*)(w2T + (size_t)(nf*16 + r)*FFN_ + wv*256 + ks + g*8);
      acc2[nf] = __builtin_amdgcn_mfma_f32_16x16x32_bf16(a, bb, acc2[nf], 0, 0, 0);
    }
  }
  #pragma unroll
  for (int nf = 0; nf < 5; ++nf)
    #pragma unroll
    for (int rr = 0; rr < 4; ++rr)
      red[wv][g*4 + rr][nf*16 + r] = acc2[nf][rr];
  __syncthreads();

  for (int e = tid; e < 16*D_; e += 512) {
    int row = e / D_, col = e % D_;
    float s = red[0][row][col];
    #pragma unroll
    for (int w = 1; w < 8; ++w) s += red[w][row][col];
    red[0][row][col] = s + b2[col] + res[(size_t)(bm+row)*D_ + col];
  }
  __syncthreads();
  if (tid < 256) {
    int row = tid >> 4, j = tid & 15;
    float v[5], s = 0.f, ss = 0.f;
    #pragma unroll
    for (int c = 0; c < 5; ++c) {
      v[c] = red[0][row][j + c*16];
      s += v[c]; ss += v[c]*v[c];
    }
    s  += __shfl_xor(s, 1, 16);  ss += __shfl_xor(ss, 1, 16);
    s  += __shfl_xor(s, 2, 16);  ss += __shfl_xor(ss, 2, 16);
    s  += __shfl_xor(s, 4, 16);  ss += __shfl_xor(ss, 4, 16);
    s  += __shfl_xor(s, 8, 16);  ss += __shfl_xor(ss, 8, 16);
    float mean = s * (1.f/D_);
    float var  = ss * (1.f/D_) - mean*mean;
    float inv  = rsqrtf(var + EPS_);
    int grow = bm + row;
    float xs[5];
    float s2 = 0.f, ss2 = 0.f;
    #pragma unroll
    for (int c = 0; c < 5; ++c) {
      int col = j + c*16;
      xs[c] = (v[c] - mean) * inv * low[col] + lob[col];
      x[(size_t)grow*D_ + col] = xs[c];
      s2 += xs[c]; ss2 += xs[c]*xs[c];
    }
    if (mode == 0) {
      s2  += __shfl_xor(s2, 1, 16);  ss2 += __shfl_xor(ss2, 1, 16);
      s2  += __shfl_xor(s2, 2, 16);  ss2 += __shfl_xor(ss2, 2, 16);
      s2  += __shfl_xor(s2, 4, 16);  ss2 += __shfl_xor(ss2, 4, 16);
      s2  += __shfl_xor(s2, 8, 16);  ss2 += __shfl_xor(ss2, 8, 16);
      float m2 = s2 * (1.f/D_);
      float v2 = ss2 * (1.f/D_) - m2*m2;
      float i2 = rsqrtf(v2 + EPS_);
      #pragma unroll
      for (int c = 0; c < 5; ++c) {
        int col = j + c*16;
        xnbf[(size_t)grow*KP_ + col] = f2bf((xs[c] - m2) * i2 * liw[col] + lib[col]);
      }
    } else {
      #pragma unroll
      for (int c = 0; c < 5; ++c)
        xnbf[(size_t)grow*KP_ + j + c*16] = f2bf(xs[c]);
    }
    xnbf[(size_t)grow*KP_ + D_ + j] = 0;
  }
}

// ============ final proj MFMA: u[2048x96] @ pwT -> out [2048x768] ============
__global__ __launch_bounds__(256) void k_proj_mfma(const ushort_t* __restrict__ xbf,
    const ushort_t* __restrict__ pwT, const float* __restrict__ pb,
    float* __restrict__ out) {
  int wv = threadIdx.x >> 6, lane = threadIdx.x & 63;
  int bm = blockIdx.x * 64;
  int bn = blockIdx.y * 128 + wv*32;
  int b  = blockIdx.z;
  int r = lane & 15, g = lane >> 4;
  f32x4 acc[4][2] = {};
  const ushort_t* Ab = xbf + ((size_t)(b*L_ + RCT_ + bm) + r)*KP_ + g*8;
  const ushort_t* Bb = pwT + (size_t)(bn + r)*KP_ + g*8;
  #pragma unroll
  for (int ks = 0; ks < KP_; ks += 32) {
    bf16x8 a[4], bfr[2];
    #pragma unroll
    for (int mf = 0; mf < 4; ++mf) a[mf]   = *(const bf16x8*)(Ab + mf*16*KP_ + ks);
    #pragma unroll
    for (int nf = 0; nf < 2; ++nf) bfr[nf] = *(const bf16x8*)(Bb + nf*16*KP_ + ks);
    #pragma unroll
    for (int mf = 0; mf < 4; ++mf)
      #pragma unroll
      for (int nf = 0; nf < 2; ++nf)
        acc[mf][nf] = __builtin_amdgcn_mfma_f32_16x16x32_bf16(a[mf], bfr[nf], acc[mf][nf], 0, 0, 0);
  }
  #pragma unroll
  for (int mf = 0; mf < 4; ++mf)
    #pragma unroll
    for (int nf = 0; nf < 2; ++nf) {
      int col = bn + nf*16 + r;
      float bc = pb[col];
      #pragma unroll
      for (int rr = 0; rr < 4; ++rr) {
        int row = bm + mf*16 + g*4 + rr;
        out[((size_t)b*TU_ + row)*OUTD_ + col] = acc[mf][nf][rr] + bc;
      }
    }
}

__global__ void k_len(const int* __restrict__ len, float* __restrict__ out) {
  int t = threadIdx.x;
  if (t < B_) out[t] = (float)len[t];
}

extern "C" void kernel_launch(void* const* d_in, const int* in_sizes, int n_in,
                              void* d_out, int out_size, void* d_ws, size_t ws_size,
                              hipStream_t stream) {
  const float* mel     = (const float*)d_in[0];
  const int*   lengths = (const int*)  d_in[1];
  const float* ln_in_w = (const float*)d_in[2];
  const float* ln_in_b = (const float*)d_in[3];
  const float* wq      = (const float*)d_in[4];
  const float* bq      = (const float*)d_in[5];
  const float* wkv     = (const float*)d_in[6];
  const float* bkv     = (const float*)d_in[7];
  const float* wo      = (const float*)d_in[8];
  const float* bo      = (const float*)d_in[9];
  const float* ln_ff_w = (const float*)d_in[10];
  const float* ln_ff_b = (const float*)d_in[11];
  const float* w1      = (const float*)d_in[12];
  const float* b1      = (const float*)d_in[13];
  const float* w2      = (const float*)d_in[14];
  const float* b2      = (const float*)d_in[15];
  const float* ln_o_w  = (const float*)d_in[16];
  const float* ln_o_b  = (const float*)d_in[17];
  const float* pw      = (const float*)d_in[18];
  const float* pb      = (const float*)d_in[19];
  float* out = (float*)d_out;

  float* ws = (float*)d_ws;
  float* x     = ws; ws += NR_*D_;
  float* resb  = ws; ws += NR_*D_;
  float* bqkv  = ws; ws += NLAYERS_*240;
  ushort_t* us = (ushort_t*)ws;
  ushort_t* xnbf  = us; us += NR_*KP_;
  ushort_t* hnbf  = us; us += NR_*KP_;
  ushort_t* w1T   = us; us += S1_;
  ushort_t* w2T   = us; us += S2_;
  ushort_t* wqkvT = us; us += S3_;
  ushort_t* woT   = us; us += S4_;
  ushort_t* pwT   = us; us += S5_;

  k_wprep<<<(WPREP_N_ + 255)/256, 256, 0, stream>>>(w1, w2, wq, wkv, wo, pw, bq, bkv,
                                                    w1T, w2T, wqkvT, woT, pwT, bqkv);
  k_build_ln<<<NR_, 128, 0, stream>>>(mel, ln_in_w, ln_in_b, x, xnbf);

  for (int l = 0; l < NLAYERS_; ++l) {
    k_attn_mega<<<dim3(NSEG_, B_), 512, 0, stream>>>(xnbf, x,
        wqkvT + l*256*KP_, bqkv + l*240, woT + l*D_*KP_, bo + l*D_,
        ln_ff_w + l*D_, ln_ff_b + l*D_, resb, hnbf);
    int last = (l == NLAYERS_-1);
    k_ffn_fused<<<NR_/16, 512, 0, stream>>>(hnbf, w1T + l*FFN_*KP_, b1 + l*FFN_,
        w2T + l*D_*FFN_, b2 + l*D_, resb,
        ln_o_w + l*D_, ln_o_b + l*D_,
        ln_in_w + (last ? 0 : (l+1)*D_), ln_in_b + (last ? 0 : (l+1)*D_),
        last, x, xnbf);
  }

  k_proj_mfma<<<dim3(TU_/64, OUTD_/128, B_), 256, 0, stream>>>(xnbf, pwT, pb, out);
  k_len<<<1, 64, 0, stream>>>(lengths, out + (size_t)B_*TU_*OUTD_);
}

// Round 6
// 176.755 us; speedup vs baseline: 2.3440x; 2.3440x over previous
//
#include <hip/hip_runtime.h>
#include <math.h>

#define B_    2
#define TU_   1024
#define D_    80
#define H_    8
#define DH_   10
#define FFN_  2048
#define SEG_  32
#define RC_   8
#define LC_   50
#define NSEG_ 32
#define RCT_  256
#define L_    1280
#define NLAYERS_ 4
#define OUTD_ 768
#define EPS_  1e-5f
#define SCALE_ 0.31622776601683794f
#define NR_   (B_*L_)                 // 2560
#define KP_   96                      // K pad 80->96

typedef __attribute__((ext_vector_type(8))) short bf16x8;
typedef __attribute__((ext_vector_type(4))) float f32x4;
typedef unsigned short ushort_t;

__device__ inline ushort_t f2bf(float f) {
  union { float f; unsigned u; } x; x.f = f;
  unsigned r = x.u + 0x7fffu + ((x.u >> 16) & 1u);   // RNE
  return (ushort_t)(r >> 16);
}

// ============ one-shot weight prep ============
#define S1_ (NLAYERS_*FFN_*KP_)        // w1T [l][n2048][k96]
#define S2_ (NLAYERS_*D_*FFN_)         // w2T [l][n80][k2048]
#define S3_ (NLAYERS_*256*KP_)         // wqkvT [l][n256][k96] (scale folded in q cols)
#define S4_ (NLAYERS_*D_*KP_)          // woT [l][n80][k96]
#define S5_ (OUTD_*KP_)                // pwT [n768][k96]
#define S6_ (NLAYERS_*240)             // bqkv fp32 [l][240]
#define WPREP_N_ (S1_+S2_+S3_+S4_+S5_+S6_)

__global__ void k_wprep(const float* __restrict__ w1, const float* __restrict__ w2,
    const float* __restrict__ wq, const float* __restrict__ wkv,
    const float* __restrict__ wo, const float* __restrict__ pw,
    const float* __restrict__ bq, const float* __restrict__ bkv,
    ushort_t* __restrict__ w1T, ushort_t* __restrict__ w2T,
    ushort_t* __restrict__ wqkvT, ushort_t* __restrict__ woT,
    ushort_t* __restrict__ pwT, float* __restrict__ bqkv) {
  int idx = blockIdx.x * blockDim.x + threadIdx.x;
  if (idx < S1_) {
    int k = idx % KP_, n = (idx / KP_) % FFN_, l = idx / (KP_*FFN_);
    w1T[idx] = (k < D_) ? f2bf(w1[(l*D_ + k)*FFN_ + n]) : 0;
    return;
  }
  idx -= S1_;
  if (idx < S2_) {
    int k = idx % FFN_, n = (idx / FFN_) % D_, l = idx / (FFN_*D_);
    w2T[idx] = f2bf(w2[(l*FFN_ + k)*D_ + n]);
    return;
  }
  idx -= S2_;
  if (idx < S3_) {
    int k = idx % KP_, n = (idx / KP_) % 256, l = idx / (KP_*256);
    float v = 0.f;
    if (k < D_ && n < 240) {
      if (n < D_) v = wq[(l*D_ + k)*D_ + n] * SCALE_;
      else        v = wkv[(l*D_ + k)*2*D_ + (n - D_)];
    }
    wqkvT[idx] = f2bf(v);
    return;
  }
  idx -= S3_;
  if (idx < S4_) {
    int k = idx % KP_, n = (idx / KP_) % D_, l = idx / (KP_*D_);
    woT[idx] = (k < D_) ? f2bf(wo[(l*D_ + k)*D_ + n]) : 0;
    return;
  }
  idx -= S4_;
  if (idx < S5_) {
    int k = idx % KP_, n = idx / KP_;
    pwT[idx] = (k < D_) ? f2bf(pw[k*OUTD_ + n]) : 0;
    return;
  }
  idx -= S5_;
  if (idx < S6_) {
    int c = idx % 240, l = idx / 240;
    bqkv[idx] = (c < D_) ? bq[l*D_ + c] * SCALE_ : bkv[l*2*D_ + (c - D_)];
  }
}

// ============ build x (gather) + layer-0 LN_in -> xnbf ============
__global__ __launch_bounds__(128) void k_build_ln(const float* __restrict__ mel,
    const float* __restrict__ lw, const float* __restrict__ lb,
    float* __restrict__ x, ushort_t* __restrict__ xnbf) {
  int row = blockIdx.x, tid = threadIdx.x;
  int b = row / L_, i = row % L_;
  int srow;
  if (i < RCT_) { int seg = i / RC_, j = i % RC_; srow = (seg+1)*SEG_ + j; }
  else          { srow = i - RCT_; }
  __shared__ float s1[128], s2[128];
  float v = (tid < D_) ? mel[(b*(TU_+RC_) + srow)*D_ + tid] : 0.f;
  if (tid < D_) x[row*D_ + tid] = v;
  s1[tid] = v; s2[tid] = v*v;
  __syncthreads();
  for (int off = 64; off > 0; off >>= 1) {
    if (tid < off) { s1[tid] += s1[tid+off]; s2[tid] += s2[tid+off]; }
    __syncthreads();
  }
  float mean = s1[0] * (1.f/D_);
  float var  = s2[0] * (1.f/D_) - mean*mean;
  float inv  = rsqrtf(var + EPS_);
  if (tid < D_)       xnbf[row*KP_ + tid] = f2bf((v - mean) * inv * lw[tid] + lb[tid]);
  else if (tid < KP_) xnbf[row*KP_ + tid] = 0;
}

// ============ QKV MFMA (layer 0 only): [2560x96] @ [96x256pad] -> q/kv fp32 ============
__global__ __launch_bounds__(256) void k_qkv_mfma(const ushort_t* __restrict__ xnbf,
    const ushort_t* __restrict__ wqkvT, const float* __restrict__ bqkv,
    float* __restrict__ q, float* __restrict__ kv) {
  int wv = threadIdx.x >> 6, lane = threadIdx.x & 63;
  int bm = blockIdx.x * 64;
  int bn = blockIdx.y * 128 + wv*32;
  int r = lane & 15, g = lane >> 4;
  f32x4 acc[4][2] = {};
  const ushort_t* Ab = xnbf + (size_t)(bm + r)*KP_ + g*8;
  const ushort_t* Bb = wqkvT + (size_t)(bn + r)*KP_ + g*8;
  #pragma unroll
  for (int ks = 0; ks < KP_; ks += 32) {
    bf16x8 a[4], bfr[2];
    #pragma unroll
    for (int mf = 0; mf < 4; ++mf) a[mf]   = *(const bf16x8*)(Ab + mf*16*KP_ + ks);
    #pragma unroll
    for (int nf = 0; nf < 2; ++nf) bfr[nf] = *(const bf16x8*)(Bb + nf*16*KP_ + ks);
    #pragma unroll
    for (int mf = 0; mf < 4; ++mf)
      #pragma unroll
      for (int nf = 0; nf < 2; ++nf)
        acc[mf][nf] = __builtin_amdgcn_mfma_f32_16x16x32_bf16(a[mf], bfr[nf], acc[mf][nf], 0, 0, 0);
  }
  #pragma unroll
  for (int mf = 0; mf < 4; ++mf)
    #pragma unroll
    for (int nf = 0; nf < 2; ++nf) {
      int col = bn + nf*16 + r;
      if (col >= 240) continue;
      float bc = bqkv[col];
      #pragma unroll
      for (int rr = 0; rr < 4; ++rr) {
        int row = bm + mf*16 + g*4 + rr;
        float v = acc[mf][nf][rr] + bc;
        if (col < D_) q[row*D_ + col] = v;
        else          kv[row*2*D_ + (col - D_)] = v;
      }
    }
}

// ============ block-sparse attention -> attb bf16 [2560][96] ============
__global__ __launch_bounds__(256) void k_attn(const float* __restrict__ q,
    const float* __restrict__ kv, ushort_t* __restrict__ att) {
  int seg = blockIdx.x, b = blockIdx.y, h = blockIdx.z;
  int tid = threadIdx.x;
  int seg_start = seg*SEG_ - LC_; if (seg_start < 0) seg_start = 0;
  int kc = RC_ + (seg+1)*SEG_ - seg_start;       // <= 90
  __shared__ float Ksh[90][DH_];
  __shared__ float Vsh[90][DH_];
  __shared__ float Qsh[40][DH_];
  __shared__ float Ssh[40][90];
  __shared__ float inv_sh[40];
  for (int idx = tid; idx < kc*DH_; idx += 256) {
    int kk = idx / DH_, d = idx % DH_;
    int krow = (kk < RC_) ? seg*RC_ + kk : RCT_ + seg_start + (kk - RC_);
    const float* base = kv + (b*L_ + krow)*2*D_ + h*DH_ + d;
    Ksh[kk][d] = base[0];
    Vsh[kk][d] = base[D_];
  }
  for (int idx = tid; idx < 40*DH_; idx += 256) {
    int qi = idx / DH_, d = idx % DH_;
    int qrow = (qi < RC_) ? seg*RC_ + qi : RCT_ + seg*SEG_ + (qi - RC_);
    Qsh[qi][d] = q[(b*L_ + qrow)*D_ + h*DH_ + d];
  }
  __syncthreads();
  for (int p = tid; p < 40*kc; p += 256) {
    int qi = p / kc, kk = p - qi*kc;
    float s = 0.f;
    #pragma unroll
    for (int d = 0; d < DH_; ++d) s += Qsh[qi][d] * Ksh[kk][d];
    Ssh[qi][kk] = s;
  }
  __syncthreads();
  if (tid < 160) {
    int row = tid >> 2, j = tid & 3;
    float pm = -INFINITY;
    for (int kk = j; kk < kc; kk += 4) pm = fmaxf(pm, Ssh[row][kk]);
    pm = fmaxf(pm, __shfl_xor(pm, 1, 4));
    pm = fmaxf(pm, __shfl_xor(pm, 2, 4));
    float ps = 0.f;
    for (int kk = j; kk < kc; kk += 4) {
      float e = expf(Ssh[row][kk] - pm);
      Ssh[row][kk] = e;
      ps += e;
    }
    ps += __shfl_xor(ps, 1, 4);
    ps += __shfl_xor(ps, 2, 4);
    if (j == 0) inv_sh[row] = 1.f / ps;
  }
  __syncthreads();
  for (int o = tid; o < 40*DH_; o += 256) {
    int qi = o / DH_, d = o - qi*DH_;
    float acc = 0.f;
    for (int kk = 0; kk < kc; ++kk) acc += Ssh[qi][kk] * Vsh[kk][d];
    int qrow = (qi < RC_) ? seg*RC_ + qi : RCT_ + seg*SEG_ + (qi - RC_);
    att[(b*L_ + qrow)*KP_ + h*DH_ + d] = f2bf(acc * inv_sh[qi]);
  }
  if (h == 0) {  // zero K-pad cols 80..95
    for (int idx = tid; idx < 40*16; idx += 256) {
      int qi = idx >> 4, c = D_ + (idx & 15);
      int qrow = (qi < RC_) ? seg*RC_ + qi : RCT_ + seg*SEG_ + (qi - RC_);
      att[(b*L_ + qrow)*KP_ + c] = 0;
    }
  }
}

// ============ WO MFMA + bias + residual + LN_ff -> res fp32, hnbf bf16 ============
__global__ __launch_bounds__(64) void k_wo_res_ln(const ushort_t* __restrict__ attb,
    const ushort_t* __restrict__ woT, const float* __restrict__ bo,
    const float* __restrict__ x, float* __restrict__ res,
    const float* __restrict__ lw, const float* __restrict__ lb,
    ushort_t* __restrict__ hnbf) {
  int lane = threadIdx.x;
  int bm = blockIdx.x * 16;
  int r = lane & 15, g = lane >> 4;
  f32x4 acc[5] = {};
  const ushort_t* Ab = attb + (size_t)(bm + r)*KP_ + g*8;
  const ushort_t* Bb = woT + (size_t)r*KP_ + g*8;
  #pragma unroll
  for (int ks = 0; ks < KP_; ks += 32) {
    bf16x8 a = *(const bf16x8*)(Ab + ks);
    #pragma unroll
    for (int nf = 0; nf < 5; ++nf) {
      bf16x8 bf = *(const bf16x8*)(Bb + nf*16*KP_ + ks);
      acc[nf] = __builtin_amdgcn_mfma_f32_16x16x32_bf16(a, bf, acc[nf], 0, 0, 0);
    }
  }
  float lwv[5], lbv[5], bov[5];
  #pragma unroll
  for (int nf = 0; nf < 5; ++nf) {
    int col = nf*16 + r;
    lwv[nf] = lw[col]; lbv[nf] = lb[col]; bov[nf] = bo[col];
  }
  #pragma unroll
  for (int rr = 0; rr < 4; ++rr) {
    int row = bm + g*4 + rr;
    float v[5];
    float s = 0.f, ss = 0.f;
    #pragma unroll
    for (int nf = 0; nf < 5; ++nf) {
      int col = nf*16 + r;
      v[nf] = acc[nf][rr] + bov[nf] + x[(size_t)row*D_ + col];
      res[(size_t)row*D_ + col] = v[nf];
      s += v[nf]; ss += v[nf]*v[nf];
    }
    s  += __shfl_xor(s, 1, 16);  ss += __shfl_xor(ss, 1, 16);
    s  += __shfl_xor(s, 2, 16);  ss += __shfl_xor(ss, 2, 16);
    s  += __shfl_xor(s, 4, 16);  ss += __shfl_xor(ss, 4, 16);
    s  += __shfl_xor(s, 8, 16);  ss += __shfl_xor(ss, 8, 16);
    float mean = s * (1.f/D_);
    float var  = ss * (1.f/D_) - mean*mean;
    float inv  = rsqrtf(var + EPS_);
    #pragma unroll
    for (int nf = 0; nf < 5; ++nf) {
      int col = nf*16 + r;
      hnbf[(size_t)row*KP_ + col] = f2bf((v[nf] - mean) * inv * lwv[nf] + lbv[nf]);
    }
    hnbf[(size_t)row*KP_ + D_ + r] = 0;
  }
}

// ============ fused FFN (+ next-layer QKV): FFN1 -> LDS -> FFN2 -> reduce+res+LN_out
//              -> x, LN_in(next) -> xnbf (+hnsh) -> QKV MFMA -> q/kv ============
// grid 160, 512 thr. 16 rows/block; wave wv owns ff1 cols [wv*256, (wv+1)*256).
__global__ __launch_bounds__(512) void k_ffn_fused(const ushort_t* __restrict__ hnbf,
    const ushort_t* __restrict__ w1T, const float* __restrict__ b1,
    const ushort_t* __restrict__ w2T, const float* __restrict__ b2,
    const float* __restrict__ res,
    const float* __restrict__ low, const float* __restrict__ lob,
    const float* __restrict__ liw, const float* __restrict__ lib, int mode,
    float* __restrict__ x, ushort_t* __restrict__ xnbf,
    const ushort_t* __restrict__ wqkvT_n, const float* __restrict__ bqkv_n,
    float* __restrict__ q, float* __restrict__ kv) {
  int tid = threadIdx.x;
  int wv = tid >> 6, lane = tid & 63;
  int r = lane & 15, g = lane >> 4;
  int bm = blockIdx.x * 16;
  __shared__ ushort_t hnsh[16][KP_];
  __shared__ ushort_t ff1sh[8][16][264];
  __shared__ float red[8][16][D_];

  if (tid < 192) {
    int row = tid / 12, c = (tid % 12) * 8;
    *(bf16x8*)&hnsh[row][c] = *(const bf16x8*)(hnbf + (size_t)(bm+row)*KP_ + c);
  }
  __syncthreads();

  // FFN1: M=16 x N=256(per wave) x K=96
  f32x4 acc1[16];
  #pragma unroll
  for (int ni = 0; ni < 16; ++ni) acc1[ni] = (f32x4){0.f,0.f,0.f,0.f};
  int nbase = wv*256;
  #pragma unroll
  for (int ks = 0; ks < KP_; ks += 32) {
    bf16x8 a = *(const bf16x8*)(&hnsh[r][ks + g*8]);
    #pragma unroll
    for (int ni = 0; ni < 16; ++ni) {
      bf16x8 bb = *(const bf16x8*)(w1T + (size_t)(nbase + ni*16 + r)*KP_ + ks + g*8);
      acc1[ni] = __builtin_amdgcn_mfma_f32_16x16x32_bf16(a, bb, acc1[ni], 0, 0, 0);
    }
  }
  #pragma unroll
  for (int ni = 0; ni < 16; ++ni) {
    int col = nbase + ni*16 + r;
    float bc = b1[col];
    #pragma unroll
    for (int rr = 0; rr < 4; ++rr)
      ff1sh[wv][g*4 + rr][ni*16 + r] = f2bf(fmaxf(acc1[ni][rr] + bc, 0.f));
  }
  // same-wave write->read of ff1sh[wv]: compiler-ordered, no block barrier needed

  // FFN2: M=16 x N=80 x K=256 (this wave's chunk)
  f32x4 acc2[5] = {};
  #pragma unroll
  for (int ks = 0; ks < 256; ks += 32) {
    bf16x8 a = *(const bf16x8*)(&ff1sh[wv][r][ks + g*8]);
    #pragma unroll
    for (int nf = 0; nf < 5; ++nf) {
      bf16x8 bb = *(const bf16x8*)(w2T + (size_t)(nf*16 + r)*FFN_ + wv*256 + ks + g*8);
      acc2[nf] = __builtin_amdgcn_mfma_f32_16x16x32_bf16(a, bb, acc2[nf], 0, 0, 0);
    }
  }
  #pragma unroll
  for (int nf = 0; nf < 5; ++nf)
    #pragma unroll
    for (int rr = 0; rr < 4; ++rr)
      red[wv][g*4 + rr][nf*16 + r] = acc2[nf][rr];
  __syncthreads();

  for (int e = tid; e < 16*D_; e += 512) {
    int row = e / D_, col = e % D_;
    float s = red[0][row][col];
    #pragma unroll
    for (int w = 1; w < 8; ++w) s += red[w][row][col];
    red[0][row][col] = s + b2[col] + res[(size_t)(bm+row)*D_ + col];
  }
  __syncthreads();
  if (tid < 256) {
    int row = tid >> 4, j = tid & 15;
    float v[5], s = 0.f, ss = 0.f;
    #pragma unroll
    for (int c = 0; c < 5; ++c) {
      v[c] = red[0][row][j + c*16];
      s += v[c]; ss += v[c]*v[c];
    }
    s  += __shfl_xor(s, 1, 16);  ss += __shfl_xor(ss, 1, 16);
    s  += __shfl_xor(s, 2, 16);  ss += __shfl_xor(ss, 2, 16);
    s  += __shfl_xor(s, 4, 16);  ss += __shfl_xor(ss, 4, 16);
    s  += __shfl_xor(s, 8, 16);  ss += __shfl_xor(ss, 8, 16);
    float mean = s * (1.f/D_);
    float var  = ss * (1.f/D_) - mean*mean;
    float inv  = rsqrtf(var + EPS_);
    int grow = bm + row;
    float xs[5];
    float s2 = 0.f, ss2 = 0.f;
    #pragma unroll
    for (int c = 0; c < 5; ++c) {
      int col = j + c*16;
      xs[c] = (v[c] - mean) * inv * low[col] + lob[col];
      x[(size_t)grow*D_ + col] = xs[c];
      s2 += xs[c]; ss2 += xs[c]*xs[c];
    }
    if (mode == 0) {
      s2  += __shfl_xor(s2, 1, 16);  ss2 += __shfl_xor(ss2, 1, 16);
      s2  += __shfl_xor(s2, 2, 16);  ss2 += __shfl_xor(ss2, 2, 16);
      s2  += __shfl_xor(s2, 4, 16);  ss2 += __shfl_xor(ss2, 4, 16);
      s2  += __shfl_xor(s2, 8, 16);  ss2 += __shfl_xor(ss2, 8, 16);
      float m2 = s2 * (1.f/D_);
      float v2 = ss2 * (1.f/D_) - m2*m2;
      float i2 = rsqrtf(v2 + EPS_);
      #pragma unroll
      for (int c = 0; c < 5; ++c) {
        int col = j + c*16;
        ushort_t bv = f2bf((xs[c] - m2) * i2 * liw[col] + lib[col]);
        xnbf[(size_t)grow*KP_ + col] = bv;
        hnsh[row][col] = bv;               // stage for fused QKV
      }
      hnsh[row][D_ + j] = 0;
    } else {
      #pragma unroll
      for (int c = 0; c < 5; ++c)
        xnbf[(size_t)grow*KP_ + j + c*16] = f2bf(xs[c]);
    }
    xnbf[(size_t)grow*KP_ + D_ + j] = 0;
  }

  // ---- fused next-layer QKV: [16x96] @ [96x240] (15 N-tiles over 8 waves) ----
  if (mode == 0) {
    __syncthreads();
    for (int t = wv; t < 15; t += 8) {
      f32x4 acc = {};
      #pragma unroll
      for (int ks = 0; ks < KP_; ks += 32) {
        bf16x8 a  = *(const bf16x8*)(&hnsh[r][ks + g*8]);
        bf16x8 bb = *(const bf16x8*)(wqkvT_n + (size_t)(t*16 + r)*KP_ + ks + g*8);
        acc = __builtin_amdgcn_mfma_f32_16x16x32_bf16(a, bb, acc, 0, 0, 0);
      }
      int col = t*16 + r;
      float bc = bqkv_n[col];
      #pragma unroll
      for (int rr = 0; rr < 4; ++rr) {
        int row = bm + g*4 + rr;
        float v = acc[rr] + bc;
        if (col < D_) q[(size_t)row*D_ + col] = v;
        else          kv[(size_t)row*2*D_ + (col - D_)] = v;
      }
    }
  }
}

// ============ final proj MFMA ============
__global__ __launch_bounds__(256) void k_proj_mfma(const ushort_t* __restrict__ xbf,
    const ushort_t* __restrict__ pwT, const float* __restrict__ pb,
    float* __restrict__ out) {
  int wv = threadIdx.x >> 6, lane = threadIdx.x & 63;
  int bm = blockIdx.x * 64;
  int bn = blockIdx.y * 128 + wv*32;
  int b  = blockIdx.z;
  int r = lane & 15, g = lane >> 4;
  f32x4 acc[4][2] = {};
  const ushort_t* Ab = xbf + ((size_t)(b*L_ + RCT_ + bm) + r)*KP_ + g*8;
  const ushort_t* Bb = pwT + (size_t)(bn + r)*KP_ + g*8;
  #pragma unroll
  for (int ks = 0; ks < KP_; ks += 32) {
    bf16x8 a[4], bfr[2];
    #pragma unroll
    for (int mf = 0; mf < 4; ++mf) a[mf]   = *(const bf16x8*)(Ab + mf*16*KP_ + ks);
    #pragma unroll
    for (int nf = 0; nf < 2; ++nf) bfr[nf] = *(const bf16x8*)(Bb + nf*16*KP_ + ks);
    #pragma unroll
    for (int mf = 0; mf < 4; ++mf)
      #pragma unroll
      for (int nf = 0; nf < 2; ++nf)
        acc[mf][nf] = __builtin_amdgcn_mfma_f32_16x16x32_bf16(a[mf], bfr[nf], acc[mf][nf], 0, 0, 0);
  }
  #pragma unroll
  for (int mf = 0; mf < 4; ++mf)
    #pragma unroll
    for (int nf = 0; nf < 2; ++nf) {
      int col = bn + nf*16 + r;
      float bc = pb[col];
      #pragma unroll
      for (int rr = 0; rr < 4; ++rr) {
        int row = bm + mf*16 + g*4 + rr;
        out[((size_t)b*TU_ + row)*OUTD_ + col] = acc[mf][nf][rr] + bc;
      }
    }
}

__global__ void k_len(const int* __restrict__ len, float* __restrict__ out) {
  int t = threadIdx.x;
  if (t < B_) out[t] = (float)len[t];
}

extern "C" void kernel_launch(void* const* d_in, const int* in_sizes, int n_in,
                              void* d_out, int out_size, void* d_ws, size_t ws_size,
                              hipStream_t stream) {
  const float* mel     = (const float*)d_in[0];
  const int*   lengths = (const int*)  d_in[1];
  const float* ln_in_w = (const float*)d_in[2];
  const float* ln_in_b = (const float*)d_in[3];
  const float* wq      = (const float*)d_in[4];
  const float* bq      = (const float*)d_in[5];
  const float* wkv     = (const float*)d_in[6];
  const float* bkv     = (const float*)d_in[7];
  const float* wo      = (const float*)d_in[8];
  const float* bo      = (const float*)d_in[9];
  const float* ln_ff_w = (const float*)d_in[10];
  const float* ln_ff_b = (const float*)d_in[11];
  const float* w1      = (const float*)d_in[12];
  const float* b1      = (const float*)d_in[13];
  const float* w2      = (const float*)d_in[14];
  const float* b2      = (const float*)d_in[15];
  const float* ln_o_w  = (const float*)d_in[16];
  const float* ln_o_b  = (const float*)d_in[17];
  const float* pw      = (const float*)d_in[18];
  const float* pb      = (const float*)d_in[19];
  float* out = (float*)d_out;

  float* ws = (float*)d_ws;
  float* x     = ws; ws += NR_*D_;
  float* resb  = ws; ws += NR_*D_;
  float* qb    = ws; ws += NR_*D_;
  float* kvb   = ws; ws += NR_*2*D_;
  float* bqkv  = ws; ws += NLAYERS_*240;
  ushort_t* us = (ushort_t*)ws;
  ushort_t* xnbf  = us; us += NR_*KP_;
  ushort_t* attbf = us; us += NR_*KP_;
  ushort_t* hnbf  = us; us += NR_*KP_;
  ushort_t* w1T   = us; us += S1_;
  ushort_t* w2T   = us; us += S2_;
  ushort_t* wqkvT = us; us += S3_;
  ushort_t* woT   = us; us += S4_;
  ushort_t* pwT   = us; us += S5_;

  k_wprep<<<(WPREP_N_ + 255)/256, 256, 0, stream>>>(w1, w2, wq, wkv, wo, pw, bq, bkv,
                                                    w1T, w2T, wqkvT, woT, pwT, bqkv);
  k_build_ln<<<NR_, 128, 0, stream>>>(mel, ln_in_w, ln_in_b, x, xnbf);
  k_qkv_mfma<<<dim3(NR_/64, 2), 256, 0, stream>>>(xnbf, wqkvT, bqkv, qb, kvb);

  for (int l = 0; l < NLAYERS_; ++l) {
    k_attn<<<dim3(NSEG_, B_, H_), 256, 0, stream>>>(qb, kvb, attbf);
    k_wo_res_ln<<<NR_/16, 64, 0, stream>>>(attbf, woT + l*D_*KP_, bo + l*D_, x, resb,
                                           ln_ff_w + l*D_, ln_ff_b + l*D_, hnbf);
    int last = (l == NLAYERS_-1);
    k_ffn_fused<<<NR_/16, 512, 0, stream>>>(hnbf, w1T + l*FFN_*KP_, b1 + l*FFN_,
        w2T + l*D_*FFN_, b2 + l*D_, resb,
        ln_o_w + l*D_, ln_o_b + l*D_,
        ln_in_w + (last ? 0 : (l+1)*D_), ln_in_b + (last ? 0 : (l+1)*D_),
        last, x, xnbf,
        wqkvT + (last ? 0 : (l+1)*256*KP_), bqkv + (last ? 0 : (l+1)*240),
        qb, kvb);
  }

  k_proj_mfma<<<dim3(TU_/64, OUTD_/128, B_), 256, 0, stream>>>(xnbf, pwT, pb, out);
  k_len<<<1, 64, 0, stream>>>(lengths, out + (size_t)B_*TU_*OUTD_);
}

// Round 7
// 164.738 us; speedup vs baseline: 2.5150x; 1.0729x over previous
//
#include <hip/hip_runtime.h>
#include <math.h>

#define B_    2
#define TU_   1024
#define D_    80
#define H_    8
#define DH_   10
#define FFN_  2048
#define SEG_  32
#define RC_   8
#define LC_   50
#define NSEG_ 32
#define RCT_  256
#define L_    1280
#define NLAYERS_ 4
#define OUTD_ 768
#define EPS_  1e-5f
#define SCALE_ 0.31622776601683794f
#define NR_   (B_*L_)                 // 2560
#define KP_   96                      // K pad 80->96

typedef __attribute__((ext_vector_type(8))) short bf16x8;
typedef __attribute__((ext_vector_type(4))) float f32x4;
typedef unsigned short ushort_t;

__device__ inline ushort_t f2bf(float f) {
  union { float f; unsigned u; } x; x.f = f;
  unsigned r = x.u + 0x7fffu + ((x.u >> 16) & 1u);   // RNE
  return (ushort_t)(r >> 16);
}

// ============ one-shot weight prep ============
#define S1_ (NLAYERS_*FFN_*KP_)        // w1T [l][n2048][k96]
#define S2_ (NLAYERS_*D_*FFN_)         // w2T [l][n80][k2048]
#define S3_ (NLAYERS_*256*KP_)         // wqkvT [l][n256][k96] (scale folded in q cols)
#define S4_ (NLAYERS_*D_*KP_)          // woT [l][n80][k96]
#define S5_ (OUTD_*KP_)                // pwT [n768][k96]
#define S6_ (NLAYERS_*240)             // bqkv fp32 [l][240]
#define WPREP_N_ (S1_+S2_+S3_+S4_+S5_+S6_)

__global__ void k_wprep(const float* __restrict__ w1, const float* __restrict__ w2,
    const float* __restrict__ wq, const float* __restrict__ wkv,
    const float* __restrict__ wo, const float* __restrict__ pw,
    const float* __restrict__ bq, const float* __restrict__ bkv,
    ushort_t* __restrict__ w1T, ushort_t* __restrict__ w2T,
    ushort_t* __restrict__ wqkvT, ushort_t* __restrict__ woT,
    ushort_t* __restrict__ pwT, float* __restrict__ bqkv) {
  int idx = blockIdx.x * blockDim.x + threadIdx.x;
  if (idx < S1_) {
    int k = idx % KP_, n = (idx / KP_) % FFN_, l = idx / (KP_*FFN_);
    w1T[idx] = (k < D_) ? f2bf(w1[(l*D_ + k)*FFN_ + n]) : 0;
    return;
  }
  idx -= S1_;
  if (idx < S2_) {
    int k = idx % FFN_, n = (idx / FFN_) % D_, l = idx / (FFN_*D_);
    w2T[idx] = f2bf(w2[(l*FFN_ + k)*D_ + n]);
    return;
  }
  idx -= S2_;
  if (idx < S3_) {
    int k = idx % KP_, n = (idx / KP_) % 256, l = idx / (KP_*256);
    float v = 0.f;
    if (k < D_ && n < 240) {
      if (n < D_) v = wq[(l*D_ + k)*D_ + n] * SCALE_;
      else        v = wkv[(l*D_ + k)*2*D_ + (n - D_)];
    }
    wqkvT[idx] = f2bf(v);
    return;
  }
  idx -= S3_;
  if (idx < S4_) {
    int k = idx % KP_, n = (idx / KP_) % D_, l = idx / (KP_*D_);
    woT[idx] = (k < D_) ? f2bf(wo[(l*D_ + k)*D_ + n]) : 0;
    return;
  }
  idx -= S4_;
  if (idx < S5_) {
    int k = idx % KP_, n = idx / KP_;
    pwT[idx] = (k < D_) ? f2bf(pw[k*OUTD_ + n]) : 0;
    return;
  }
  idx -= S5_;
  if (idx < S6_) {
    int c = idx % 240, l = idx / 240;
    bqkv[idx] = (c < D_) ? bq[l*D_ + c] * SCALE_ : bkv[l*2*D_ + (c - D_)];
  }
}

// ============ build x (gather) + layer-0 LN_in -> xnbf ============
__global__ __launch_bounds__(128) void k_build_ln(const float* __restrict__ mel,
    const float* __restrict__ lw, const float* __restrict__ lb,
    float* __restrict__ x, ushort_t* __restrict__ xnbf) {
  int row = blockIdx.x, tid = threadIdx.x;
  int b = row / L_, i = row % L_;
  int srow;
  if (i < RCT_) { int seg = i / RC_, j = i % RC_; srow = (seg+1)*SEG_ + j; }
  else          { srow = i - RCT_; }
  __shared__ float s1[128], s2[128];
  float v = (tid < D_) ? mel[(b*(TU_+RC_) + srow)*D_ + tid] : 0.f;
  if (tid < D_) x[row*D_ + tid] = v;
  s1[tid] = v; s2[tid] = v*v;
  __syncthreads();
  for (int off = 64; off > 0; off >>= 1) {
    if (tid < off) { s1[tid] += s1[tid+off]; s2[tid] += s2[tid+off]; }
    __syncthreads();
  }
  float mean = s1[0] * (1.f/D_);
  float var  = s2[0] * (1.f/D_) - mean*mean;
  float inv  = rsqrtf(var + EPS_);
  if (tid < D_)       xnbf[row*KP_ + tid] = f2bf((v - mean) * inv * lw[tid] + lb[tid]);
  else if (tid < KP_) xnbf[row*KP_ + tid] = 0;
}

// ============ QKV MFMA (layer 0 only) ============
__global__ __launch_bounds__(256) void k_qkv_mfma(const ushort_t* __restrict__ xnbf,
    const ushort_t* __restrict__ wqkvT, const float* __restrict__ bqkv,
    float* __restrict__ q, float* __restrict__ kv) {
  int wv = threadIdx.x >> 6, lane = threadIdx.x & 63;
  int bm = blockIdx.x * 64;
  int bn = blockIdx.y * 128 + wv*32;
  int r = lane & 15, g = lane >> 4;
  f32x4 acc[4][2] = {};
  const ushort_t* Ab = xnbf + (size_t)(bm + r)*KP_ + g*8;
  const ushort_t* Bb = wqkvT + (size_t)(bn + r)*KP_ + g*8;
  #pragma unroll
  for (int ks = 0; ks < KP_; ks += 32) {
    bf16x8 a[4], bfr[2];
    #pragma unroll
    for (int mf = 0; mf < 4; ++mf) a[mf]   = *(const bf16x8*)(Ab + mf*16*KP_ + ks);
    #pragma unroll
    for (int nf = 0; nf < 2; ++nf) bfr[nf] = *(const bf16x8*)(Bb + nf*16*KP_ + ks);
    #pragma unroll
    for (int mf = 0; mf < 4; ++mf)
      #pragma unroll
      for (int nf = 0; nf < 2; ++nf)
        acc[mf][nf] = __builtin_amdgcn_mfma_f32_16x16x32_bf16(a[mf], bfr[nf], acc[mf][nf], 0, 0, 0);
  }
  #pragma unroll
  for (int mf = 0; mf < 4; ++mf)
    #pragma unroll
    for (int nf = 0; nf < 2; ++nf) {
      int col = bn + nf*16 + r;
      if (col >= 240) continue;
      float bc = bqkv[col];
      #pragma unroll
      for (int rr = 0; rr < 4; ++rr) {
        int row = bm + mf*16 + g*4 + rr;
        float v = acc[mf][nf][rr] + bc;
        if (col < D_) q[row*D_ + col] = v;
        else          kv[row*2*D_ + (col - D_)] = v;
      }
    }
}

// ============ block-sparse attention -> attb bf16 [2560][96] ============
__global__ __launch_bounds__(256) void k_attn(const float* __restrict__ q,
    const float* __restrict__ kv, ushort_t* __restrict__ att) {
  int seg = blockIdx.x, b = blockIdx.y, h = blockIdx.z;
  int tid = threadIdx.x;
  int seg_start = seg*SEG_ - LC_; if (seg_start < 0) seg_start = 0;
  int kc = RC_ + (seg+1)*SEG_ - seg_start;       // <= 90
  __shared__ float Ksh[90][DH_];
  __shared__ float Vsh[90][DH_];
  __shared__ float Qsh[40][DH_];
  __shared__ float Ssh[40][90];
  __shared__ float inv_sh[40];
  for (int idx = tid; idx < kc*DH_; idx += 256) {
    int kk = idx / DH_, d = idx % DH_;
    int krow = (kk < RC_) ? seg*RC_ + kk : RCT_ + seg_start + (kk - RC_);
    const float* base = kv + (b*L_ + krow)*2*D_ + h*DH_ + d;
    Ksh[kk][d] = base[0];
    Vsh[kk][d] = base[D_];
  }
  for (int idx = tid; idx < 40*DH_; idx += 256) {
    int qi = idx / DH_, d = idx % DH_;
    int qrow = (qi < RC_) ? seg*RC_ + qi : RCT_ + seg*SEG_ + (qi - RC_);
    Qsh[qi][d] = q[(b*L_ + qrow)*D_ + h*DH_ + d];
  }
  __syncthreads();
  for (int p = tid; p < 40*kc; p += 256) {
    int qi = p / kc, kk = p - qi*kc;
    float s = 0.f;
    #pragma unroll
    for (int d = 0; d < DH_; ++d) s += Qsh[qi][d] * Ksh[kk][d];
    Ssh[qi][kk] = s;
  }
  __syncthreads();
  if (tid < 160) {
    int row = tid >> 2, j = tid & 3;
    float pm = -INFINITY;
    for (int kk = j; kk < kc; kk += 4) pm = fmaxf(pm, Ssh[row][kk]);
    pm = fmaxf(pm, __shfl_xor(pm, 1, 4));
    pm = fmaxf(pm, __shfl_xor(pm, 2, 4));
    float ps = 0.f;
    for (int kk = j; kk < kc; kk += 4) {
      float e = expf(Ssh[row][kk] - pm);
      Ssh[row][kk] = e;
      ps += e;
    }
    ps += __shfl_xor(ps, 1, 4);
    ps += __shfl_xor(ps, 2, 4);
    if (j == 0) inv_sh[row] = 1.f / ps;
  }
  __syncthreads();
  for (int o = tid; o < 40*DH_; o += 256) {
    int qi = o / DH_, d = o - qi*DH_;
    float acc = 0.f;
    for (int kk = 0; kk < kc; ++kk) acc += Ssh[qi][kk] * Vsh[kk][d];
    int qrow = (qi < RC_) ? seg*RC_ + qi : RCT_ + seg*SEG_ + (qi - RC_);
    att[(b*L_ + qrow)*KP_ + h*DH_ + d] = f2bf(acc * inv_sh[qi]);
  }
  if (h == 0) {  // zero K-pad cols 80..95
    for (int idx = tid; idx < 40*16; idx += 256) {
      int qi = idx >> 4, c = D_ + (idx & 15);
      int qrow = (qi < RC_) ? seg*RC_ + qi : RCT_ + seg*SEG_ + (qi - RC_);
      att[(b*L_ + qrow)*KP_ + c] = 0;
    }
  }
}

// ============ mega-fused per-layer tail: WO + res + LN_ff + FFN1 + FFN2 +
//              reduce + res + LN_out -> x, LN_in(next) -> xnbf, QKV(next) ============
// grid 160, 512 thr. 16 rows/block; wave wv owns ff1 cols [wv*256, (wv+1)*256).
__global__ __launch_bounds__(512) void k_ffn_fused(const ushort_t* __restrict__ attbf,
    const ushort_t* __restrict__ woT, const float* __restrict__ bo,
    const ushort_t* __restrict__ w1T, const float* __restrict__ b1,
    const ushort_t* __restrict__ w2T, const float* __restrict__ b2,
    const float* __restrict__ lfw, const float* __restrict__ lfb,
    const float* __restrict__ low, const float* __restrict__ lob,
    const float* __restrict__ liw, const float* __restrict__ lib, int mode,
    float* __restrict__ x, ushort_t* __restrict__ xnbf,
    const ushort_t* __restrict__ wqkvT_n, const float* __restrict__ bqkv_n,
    float* __restrict__ q, float* __restrict__ kv) {
  int tid = threadIdx.x;
  int wv = tid >> 6, lane = tid & 63;
  int r = lane & 15, g = lane >> 4;
  int bm = blockIdx.x * 16;
  __shared__ ushort_t attsh[16][KP_];
  __shared__ ushort_t hnsh[16][KP_];
  __shared__ ushort_t ff1sh[8][16][264];
  __shared__ float red[8][16][D_];
  __shared__ float vsh[16][D_];          // WO out, then +bias+residual (res)

  if (tid < 192) {
    int row = tid / 12, c = (tid % 12) * 8;
    *(bf16x8*)&attsh[row][c] = *(const bf16x8*)(attbf + (size_t)(bm+row)*KP_ + c);
  }
  __syncthreads();

  // ---- WO: waves 0..4 each compute one 16-col fragment (K=96) ----
  if (wv < 5) {
    f32x4 acc = {};
    #pragma unroll
    for (int ks = 0; ks < KP_; ks += 32) {
      bf16x8 a  = *(const bf16x8*)(&attsh[r][ks + g*8]);
      bf16x8 bb = *(const bf16x8*)(woT + (size_t)(wv*16 + r)*KP_ + ks + g*8);
      acc = __builtin_amdgcn_mfma_f32_16x16x32_bf16(a, bb, acc, 0, 0, 0);
    }
    #pragma unroll
    for (int rr = 0; rr < 4; ++rr)
      vsh[g*4 + rr][wv*16 + r] = acc[rr];
  }
  __syncthreads();

  // ---- bias + residual + LN_ff -> hnsh (res kept in vsh) ----
  if (tid < 256) {
    int row = tid >> 4, j = tid & 15;
    int grow = bm + row;
    float v[5], s = 0.f, ss = 0.f;
    #pragma unroll
    for (int c = 0; c < 5; ++c) {
      int col = j + c*16;
      v[c] = vsh[row][col] + bo[col] + x[(size_t)grow*D_ + col];
      vsh[row][col] = v[c];
      s += v[c]; ss += v[c]*v[c];
    }
    s  += __shfl_xor(s, 1, 16);  ss += __shfl_xor(ss, 1, 16);
    s  += __shfl_xor(s, 2, 16);  ss += __shfl_xor(ss, 2, 16);
    s  += __shfl_xor(s, 4, 16);  ss += __shfl_xor(ss, 4, 16);
    s  += __shfl_xor(s, 8, 16);  ss += __shfl_xor(ss, 8, 16);
    float mean = s * (1.f/D_);
    float var  = ss * (1.f/D_) - mean*mean;
    float inv  = rsqrtf(var + EPS_);
    #pragma unroll
    for (int c = 0; c < 5; ++c) {
      int col = j + c*16;
      hnsh[row][col] = f2bf((v[c] - mean) * inv * lfw[col] + lfb[col]);
    }
    hnsh[row][D_ + j] = 0;
  }
  __syncthreads();

  // ---- FFN1: M=16 x N=256(per wave) x K=96 ----
  f32x4 acc1[16];
  #pragma unroll
  for (int ni = 0; ni < 16; ++ni) acc1[ni] = (f32x4){0.f,0.f,0.f,0.f};
  int nbase = wv*256;
  #pragma unroll
  for (int ks = 0; ks < KP_; ks += 32) {
    bf16x8 a = *(const bf16x8*)(&hnsh[r][ks + g*8]);
    #pragma unroll
    for (int ni = 0; ni < 16; ++ni) {
      bf16x8 bb = *(const bf16x8*)(w1T + (size_t)(nbase + ni*16 + r)*KP_ + ks + g*8);
      acc1[ni] = __builtin_amdgcn_mfma_f32_16x16x32_bf16(a, bb, acc1[ni], 0, 0, 0);
    }
  }
  #pragma unroll
  for (int ni = 0; ni < 16; ++ni) {
    int col = nbase + ni*16 + r;
    float bc = b1[col];
    #pragma unroll
    for (int rr = 0; rr < 4; ++rr)
      ff1sh[wv][g*4 + rr][ni*16 + r] = f2bf(fmaxf(acc1[ni][rr] + bc, 0.f));
  }
  // same-wave write->read of ff1sh[wv]: compiler-ordered, no block barrier needed

  // ---- FFN2: M=16 x N=80 x K=256 (this wave's chunk) ----
  f32x4 acc2[5] = {};
  #pragma unroll
  for (int ks = 0; ks < 256; ks += 32) {
    bf16x8 a = *(const bf16x8*)(&ff1sh[wv][r][ks + g*8]);
    #pragma unroll
    for (int nf = 0; nf < 5; ++nf) {
      bf16x8 bb = *(const bf16x8*)(w2T + (size_t)(nf*16 + r)*FFN_ + wv*256 + ks + g*8);
      acc2[nf] = __builtin_amdgcn_mfma_f32_16x16x32_bf16(a, bb, acc2[nf], 0, 0, 0);
    }
  }
  #pragma unroll
  for (int nf = 0; nf < 5; ++nf)
    #pragma unroll
    for (int rr = 0; rr < 4; ++rr)
      red[wv][g*4 + rr][nf*16 + r] = acc2[nf][rr];
  __syncthreads();

  for (int e = tid; e < 16*D_; e += 512) {
    int row = e / D_, col = e % D_;
    float s = red[0][row][col];
    #pragma unroll
    for (int w = 1; w < 8; ++w) s += red[w][row][col];
    red[0][row][col] = s + b2[col] + vsh[row][col];
  }
  __syncthreads();
  if (tid < 256) {
    int row = tid >> 4, j = tid & 15;
    float v[5], s = 0.f, ss = 0.f;
    #pragma unroll
    for (int c = 0; c < 5; ++c) {
      v[c] = red[0][row][j + c*16];
      s += v[c]; ss += v[c]*v[c];
    }
    s  += __shfl_xor(s, 1, 16);  ss += __shfl_xor(ss, 1, 16);
    s  += __shfl_xor(s, 2, 16);  ss += __shfl_xor(ss, 2, 16);
    s  += __shfl_xor(s, 4, 16);  ss += __shfl_xor(ss, 4, 16);
    s  += __shfl_xor(s, 8, 16);  ss += __shfl_xor(ss, 8, 16);
    float mean = s * (1.f/D_);
    float var  = ss * (1.f/D_) - mean*mean;
    float inv  = rsqrtf(var + EPS_);
    int grow = bm + row;
    float xs[5];
    float s2 = 0.f, ss2 = 0.f;
    #pragma unroll
    for (int c = 0; c < 5; ++c) {
      int col = j + c*16;
      xs[c] = (v[c] - mean) * inv * low[col] + lob[col];
      x[(size_t)grow*D_ + col] = xs[c];
      s2 += xs[c]; ss2 += xs[c]*xs[c];
    }
    if (mode == 0) {
      s2  += __shfl_xor(s2, 1, 16);  ss2 += __shfl_xor(ss2, 1, 16);
      s2  += __shfl_xor(s2, 2, 16);  ss2 += __shfl_xor(ss2, 2, 16);
      s2  += __shfl_xor(s2, 4, 16);  ss2 += __shfl_xor(ss2, 4, 16);
      s2  += __shfl_xor(s2, 8, 16);  ss2 += __shfl_xor(ss2, 8, 16);
      float m2 = s2 * (1.f/D_);
      float v2 = ss2 * (1.f/D_) - m2*m2;
      float i2 = rsqrtf(v2 + EPS_);
      #pragma unroll
      for (int c = 0; c < 5; ++c) {
        int col = j + c*16;
        ushort_t bv = f2bf((xs[c] - m2) * i2 * liw[col] + lib[col]);
        xnbf[(size_t)grow*KP_ + col] = bv;
        hnsh[row][col] = bv;               // stage for fused QKV
      }
      hnsh[row][D_ + j] = 0;
    } else {
      #pragma unroll
      for (int c = 0; c < 5; ++c)
        xnbf[(size_t)grow*KP_ + j + c*16] = f2bf(xs[c]);
    }
    xnbf[(size_t)grow*KP_ + D_ + j] = 0;
  }

  // ---- fused next-layer QKV: [16x96] @ [96x240] (15 N-tiles over 8 waves) ----
  if (mode == 0) {
    __syncthreads();
    for (int t = wv; t < 15; t += 8) {
      f32x4 acc = {};
      #pragma unroll
      for (int ks = 0; ks < KP_; ks += 32) {
        bf16x8 a  = *(const bf16x8*)(&hnsh[r][ks + g*8]);
        bf16x8 bb = *(const bf16x8*)(wqkvT_n + (size_t)(t*16 + r)*KP_ + ks + g*8);
        acc = __builtin_amdgcn_mfma_f32_16x16x32_bf16(a, bb, acc, 0, 0, 0);
      }
      int col = t*16 + r;
      float bc = bqkv_n[col];
      #pragma unroll
      for (int rr = 0; rr < 4; ++rr) {
        int row = bm + g*4 + rr;
        float v = acc[rr] + bc;
        if (col < D_) q[(size_t)row*D_ + col] = v;
        else          kv[(size_t)row*2*D_ + (col - D_)] = v;
      }
    }
  }
}

// ============ final proj MFMA (+ lengths tail) ============
__global__ __launch_bounds__(256) void k_proj_mfma(const ushort_t* __restrict__ xbf,
    const ushort_t* __restrict__ pwT, const float* __restrict__ pb,
    const int* __restrict__ len, float* __restrict__ out) {
  int wv = threadIdx.x >> 6, lane = threadIdx.x & 63;
  int bm = blockIdx.x * 64;
  int bn = blockIdx.y * 128 + wv*32;
  int b  = blockIdx.z;
  int r = lane & 15, g = lane >> 4;
  f32x4 acc[4][2] = {};
  const ushort_t* Ab = xbf + ((size_t)(b*L_ + RCT_ + bm) + r)*KP_ + g*8;
  const ushort_t* Bb = pwT + (size_t)(bn + r)*KP_ + g*8;
  #pragma unroll
  for (int ks = 0; ks < KP_; ks += 32) {
    bf16x8 a[4], bfr[2];
    #pragma unroll
    for (int mf = 0; mf < 4; ++mf) a[mf]   = *(const bf16x8*)(Ab + mf*16*KP_ + ks);
    #pragma unroll
    for (int nf = 0; nf < 2; ++nf) bfr[nf] = *(const bf16x8*)(Bb + nf*16*KP_ + ks);
    #pragma unroll
    for (int mf = 0; mf < 4; ++mf)
      #pragma unroll
      for (int nf = 0; nf < 2; ++nf)
        acc[mf][nf] = __builtin_amdgcn_mfma_f32_16x16x32_bf16(a[mf], bfr[nf], acc[mf][nf], 0, 0, 0);
  }
  #pragma unroll
  for (int mf = 0; mf < 4; ++mf)
    #pragma unroll
    for (int nf = 0; nf < 2; ++nf) {
      int col = bn + nf*16 + r;
      float bc = pb[col];
      #pragma unroll
      for (int rr = 0; rr < 4; ++rr) {
        int row = bm + mf*16 + g*4 + rr;
        out[((size_t)b*TU_ + row)*OUTD_ + col] = acc[mf][nf][rr] + bc;
      }
    }
  if (blockIdx.x == 0 && blockIdx.y == 0 && blockIdx.z == 0 && threadIdx.x < B_)
    out[(size_t)B_*TU_*OUTD_ + threadIdx.x] = (float)len[threadIdx.x];
}

extern "C" void kernel_launch(void* const* d_in, const int* in_sizes, int n_in,
                              void* d_out, int out_size, void* d_ws, size_t ws_size,
                              hipStream_t stream) {
  const float* mel     = (const float*)d_in[0];
  const int*   lengths = (const int*)  d_in[1];
  const float* ln_in_w = (const float*)d_in[2];
  const float* ln_in_b = (const float*)d_in[3];
  const float* wq      = (const float*)d_in[4];
  const float* bq      = (const float*)d_in[5];
  const float* wkv     = (const float*)d_in[6];
  const float* bkv     = (const float*)d_in[7];
  const float* wo      = (const float*)d_in[8];
  const float* bo      = (const float*)d_in[9];
  const float* ln_ff_w = (const float*)d_in[10];
  const float* ln_ff_b = (const float*)d_in[11];
  const float* w1      = (const float*)d_in[12];
  const float* b1      = (const float*)d_in[13];
  const float* w2      = (const float*)d_in[14];
  const float* b2      = (const float*)d_in[15];
  const float* ln_o_w  = (const float*)d_in[16];
  const float* ln_o_b  = (const float*)d_in[17];
  const float* pw      = (const float*)d_in[18];
  const float* pb      = (const float*)d_in[19];
  float* out = (float*)d_out;

  float* ws = (float*)d_ws;
  float* x     = ws; ws += NR_*D_;
  float* qb    = ws; ws += NR_*D_;
  float* kvb   = ws; ws += NR_*2*D_;
  float* bqkv  = ws; ws += NLAYERS_*240;
  ushort_t* us = (ushort_t*)ws;
  ushort_t* xnbf  = us; us += NR_*KP_;
  ushort_t* attbf = us; us += NR_*KP_;
  ushort_t* w1T   = us; us += S1_;
  ushort_t* w2T   = us; us += S2_;
  ushort_t* wqkvT = us; us += S3_;
  ushort_t* woT   = us; us += S4_;
  ushort_t* pwT   = us; us += S5_;

  k_wprep<<<(WPREP_N_ + 255)/256, 256, 0, stream>>>(w1, w2, wq, wkv, wo, pw, bq, bkv,
                                                    w1T, w2T, wqkvT, woT, pwT, bqkv);
  k_build_ln<<<NR_, 128, 0, stream>>>(mel, ln_in_w, ln_in_b, x, xnbf);
  k_qkv_mfma<<<dim3(NR_/64, 2), 256, 0, stream>>>(xnbf, wqkvT, bqkv, qb, kvb);

  for (int l = 0; l < NLAYERS_; ++l) {
    k_attn<<<dim3(NSEG_, B_, H_), 256, 0, stream>>>(qb, kvb, attbf);
    int last = (l == NLAYERS_-1);
    k_ffn_fused<<<NR_/16, 512, 0, stream>>>(attbf,
        woT + l*D_*KP_, bo + l*D_,
        w1T + l*FFN_*KP_, b1 + l*FFN_,
        w2T + l*D_*FFN_, b2 + l*D_,
        ln_ff_w + l*D_, ln_ff_b + l*D_,
        ln_o_w + l*D_, ln_o_b + l*D_,
        ln_in_w + (last ? 0 : (l+1)*D_), ln_in_b + (last ? 0 : (l+1)*D_),
        last, x, xnbf,
        wqkvT + (last ? 0 : (l+1)*256*KP_), bqkv + (last ? 0 : (l+1)*240),
        qb, kvb);
  }

  k_proj_mfma<<<dim3(TU_/64, OUTD_/128, B_), 256, 0, stream>>>(xnbf, pwT, pb, lengths, out);
}